// Round 9
// baseline (439.466 us; speedup 1.0000x reference)
//
#include <hip/hip_runtime.h>

#define NN   40000
#define RR   16
#define EE   50000
#define DD   256
#define NB   4
#define KTOT (NB*DD + DD)   // 1280
#define BM   64
#define BN   128
#define BK   32
#define NITER (KTOT/BK)     // 40

#define SCAN_BLK  40
#define SCAN_ELEM 1024      // elements per scan block (40*1024 >= NN)

typedef __bf16 bf16x8 __attribute__((ext_vector_type(8)));
typedef float  f32x4  __attribute__((ext_vector_type(4)));
typedef float  f32x2  __attribute__((ext_vector_type(2)));
typedef unsigned short ushort_t;

__device__ inline unsigned short f2bf(float f) {
    unsigned int b = __builtin_bit_cast(unsigned int, f);
    b += 0x7FFFu + ((b >> 16) & 1u);      // round-to-nearest-even
    return (unsigned short)(b >> 16);
}

// ws layout (bytes), all 16B-aligned:
//   vb      @ 0            NN*1024 bf16 =  81,920,000
//   xb      @ 81,920,000   NN*256  bf16 =  20,480,000
//   Bt      @ 102,400,000  256*1280 bf16 =    655,360
//   deg     @ 103,055,360  RR*NN int    =   2,560,000
//   offsets @ 105,775,360  (NN+1) int
//   cursor  @ 105,935,376  NN int
//   recs    @ 106,095,376  RR*EE u32    =   3,200,000
//   bsum    @ 109,295,376  SCAN_BLK int

#define CAST_BLKS ((NN * DD / 4 + DD * KTOT + 255) / 256)   // 11280
#define DEG_BLKS  ((RR * EE + 255) / 256)                   // 3125

// fused: xb cast + Bt build + per-relation degree histogram
__global__ __launch_bounds__(256) void k_prep(const float* __restrict__ x,
                                              const float* __restrict__ bases,
                                              const float* __restrict__ lw,
                                              const int* __restrict__ edst,
                                              ushort_t* __restrict__ xb,
                                              ushort_t* __restrict__ Bt,
                                              int* __restrict__ deg) {
    int b = blockIdx.x;
    if (b < CAST_BLKS) {
        int t = b * 256 + threadIdx.x;
        const int NX = NN * DD / 4;
        if (t < NX) {
            float4 f = *(const float4*)(x + (size_t)t * 4);
            ushort4 o;
            o.x = f2bf(f.x); o.y = f2bf(f.y); o.z = f2bf(f.z); o.w = f2bf(f.w);
            *(ushort4*)(xb + (size_t)t * 4) = o;
        } else {
            int u = t - NX;                // u = o*1280 + k
            if (u < DD * KTOT) {
                int o = u / KTOT, k = u - o * KTOT;
                float f = (k < NB * DD) ? bases[(size_t)k * DD + o]
                                        : lw[(size_t)(k - NB * DD) * DD + o];
                Bt[u] = f2bf(f);
            }
        }
    } else {
        int e = (b - CAST_BLKS) * 256 + threadIdx.x;
        if (e < RR * EE) {
            int r = e / EE;
            atomicAdd(&deg[r * NN + edst[e]], 1);
        }
    }
}

// phase A: per-node degree sum (from deg directly) + block-local exclusive scan
__global__ __launch_bounds__(256) void k_scanA(const int* __restrict__ deg,
                                               int* __restrict__ offsets,
                                               int* __restrict__ bsum) {
    __shared__ int part[256];
    int t = threadIdx.x, b = blockIdx.x;
    int g = b * SCAN_ELEM + t * 4;
    int4 h = {0, 0, 0, 0};
    if (g < NN) {                          // NN%4==0 so g<NN implies g+3<NN
#pragma unroll
        for (int r = 0; r < RR; r++) {
            int4 d = *(const int4*)(deg + (size_t)r * NN + g);
            h.x += d.x; h.y += d.y; h.z += d.z; h.w += d.w;
        }
    }
    int s = h.x + h.y + h.z + h.w;
    part[t] = s;
    __syncthreads();
    for (int off = 1; off < 256; off <<= 1) {
        int v = (t >= off) ? part[t - off] : 0;
        __syncthreads();
        part[t] += v;
        __syncthreads();
    }
    int ex = part[t] - s;
    if (g < NN) {
        int4 o;
        o.x = ex;
        o.y = ex + h.x;
        o.z = ex + h.x + h.y;
        o.w = ex + h.x + h.y + h.z;
        *(int4*)(offsets + g) = o;
    }
    if (t == 255) bsum[b] = part[255];
}

// phase B: add block-prefix base, mirror into cursor, write offsets[NN]
__global__ __launch_bounds__(256) void k_scanB(const int* __restrict__ bsum,
                                               int* __restrict__ offsets,
                                               int* __restrict__ cursor) {
    __shared__ int sbase, stot;
    int t = threadIdx.x, b = blockIdx.x;
    if (t == 0) {
        int acc = 0, base = 0;
        for (int i = 0; i < SCAN_BLK; i++) {
            if (i == b) base = acc;
            acc += bsum[i];
        }
        sbase = base;
        stot = acc;
    }
    __syncthreads();
    int base = sbase;
    int g = b * SCAN_ELEM + t * 4;
    if (g < NN) {
        int4 o = *(const int4*)(offsets + g);
        o.x += base; o.y += base; o.z += base; o.w += base;
        *(int4*)(offsets + g) = o;
        *(int4*)(cursor + g) = o;
    }
    if (b == SCAN_BLK - 1 && t == 0) offsets[NN] = stot;
}

__global__ __launch_bounds__(256) void k_escatter(const int* __restrict__ esrc,
                                                  const int* __restrict__ edst,
                                                  int* __restrict__ cursor,
                                                  unsigned int* __restrict__ recs) {
    int e = blockIdx.x * blockDim.x + threadIdx.x;
    if (e >= RR * EE) return;
    int r = e / EE;
    int d = edst[e];
    int pos = atomicAdd(&cursor[d], 1);
    recs[pos] = (unsigned int)esrc[e] | ((unsigned int)r << 16);
}

// one wave per dst node; per-wave weight table in LDS; 4-edge unrolled
__global__ __launch_bounds__(256) void k_gather(const ushort_t* __restrict__ xb,
                                                const float* __restrict__ coeff,
                                                const int* __restrict__ deg,
                                                const int* __restrict__ offsets,
                                                const unsigned int* __restrict__ recs,
                                                ushort_t* __restrict__ vb) {
    __shared__ float wtab[4][64];
    int lane = threadIdx.x & 63;
    int wv   = threadIdx.x >> 6;
    int n    = __builtin_amdgcn_readfirstlane(blockIdx.x * 4 + wv);

    {   // wtab[wv][r*4+b] = coeff[r*4+b] / max(deg[r][n],1)
        int r  = lane >> 2;
        int dg = deg[r * NN + n];
        float inv = 1.0f / (float)(dg > 0 ? dg : 1);
        wtab[wv][lane] = coeff[lane] * inv;
    }

    int beg = offsets[n], end = offsets[n + 1];
    f32x2 a[4][2];
#pragma unroll
    for (int b = 0; b < 4; b++) { a[b][0] = (f32x2){0,0}; a[b][1] = (f32x2){0,0}; }

    const float* wrow = &wtab[wv][0];
    const ushort_t* xl = xb + lane * 4;

    auto acc_edge = [&](uint2 u, float4 w) {
        f32x2 lo, hi;
        lo.x = __builtin_bit_cast(float, u.x << 16);
        lo.y = __builtin_bit_cast(float, u.x & 0xFFFF0000u);
        hi.x = __builtin_bit_cast(float, u.y << 16);
        hi.y = __builtin_bit_cast(float, u.y & 0xFFFF0000u);
        a[0][0] = lo * (f32x2){w.x, w.x} + a[0][0];
        a[0][1] = hi * (f32x2){w.x, w.x} + a[0][1];
        a[1][0] = lo * (f32x2){w.y, w.y} + a[1][0];
        a[1][1] = hi * (f32x2){w.y, w.y} + a[1][1];
        a[2][0] = lo * (f32x2){w.z, w.z} + a[2][0];
        a[2][1] = hi * (f32x2){w.z, w.z} + a[2][1];
        a[3][0] = lo * (f32x2){w.w, w.w} + a[3][0];
        a[3][1] = hi * (f32x2){w.w, w.w} + a[3][1];
    };

    int ei = beg;
    for (; ei + 4 <= end; ei += 4) {
        unsigned int r0 = recs[ei + 0];
        unsigned int r1 = recs[ei + 1];
        unsigned int r2 = recs[ei + 2];
        unsigned int r3 = recs[ei + 3];
        uint2 u0 = *(const uint2*)(xl + (size_t)(r0 & 0xFFFFu) * DD);
        uint2 u1 = *(const uint2*)(xl + (size_t)(r1 & 0xFFFFu) * DD);
        uint2 u2 = *(const uint2*)(xl + (size_t)(r2 & 0xFFFFu) * DD);
        uint2 u3 = *(const uint2*)(xl + (size_t)(r3 & 0xFFFFu) * DD);
        float4 w0 = *(const float4*)&wrow[(r0 >> 16) * 4];
        float4 w1 = *(const float4*)&wrow[(r1 >> 16) * 4];
        float4 w2 = *(const float4*)&wrow[(r2 >> 16) * 4];
        float4 w3 = *(const float4*)&wrow[(r3 >> 16) * 4];
        acc_edge(u0, w0);
        acc_edge(u1, w1);
        acc_edge(u2, w2);
        acc_edge(u3, w3);
    }
    for (; ei < end; ei++) {
        unsigned int r0 = recs[ei];
        uint2 u0 = *(const uint2*)(xl + (size_t)(r0 & 0xFFFFu) * DD);
        float4 w0 = *(const float4*)&wrow[(r0 >> 16) * 4];
        acc_edge(u0, w0);
    }

    ushort_t* vr = vb + (size_t)n * (NB * DD) + lane * 4;
#pragma unroll
    for (int b = 0; b < 4; b++) {
        ushort4 o;
        o.x = f2bf(a[b][0].x); o.y = f2bf(a[b][0].y);
        o.z = f2bf(a[b][1].x); o.w = f2bf(a[b][1].y);
        *(ushort4*)(vr + b * DD) = o;
    }
}

// MFMA GEMM: out[40000][256] = relu([vb | xb] @ Bt^T + bias)
// block tile 64x128 (grid 625x2), 4 waves 2x2, wave tile 32x64; BK=32.
// LDS XOR swizzle: off_ushort(row,c) = row*32 + (c ^ ((row>>2)&3))*8
//   -> bankgroup = (row&1)*4 + (c ^ ((row>>2)&3)): covers all 8 groups 2-way on
//      both staging writes and fragment reads = conflict-free (m136: 2-way free).
// Double-buffered LDS + 2-deep register prefetch: g_load(k+2) consumed at
// write(k+2) -> ~2 iterations of vmcnt slack, hides HBM latency.
__global__ __launch_bounds__(256) void k_gemm(const ushort_t* __restrict__ vb,
                                              const ushort_t* __restrict__ xb,
                                              const ushort_t* __restrict__ Bt,
                                              const float* __restrict__ bias,
                                              float* __restrict__ out) {
    __shared__ ushort_t As[2][BM * BK];   // 2 x 4 KB
    __shared__ ushort_t Bs[2][BN * BK];   // 2 x 8 KB
    int tid  = threadIdx.x;
    int lane = tid & 63;
    int w    = tid >> 6;
    int wr   = w >> 1, wc = w & 1;     // wave tile: rows wr*32.., cols wc*64..
    int rowbase = blockIdx.x * BM;     // NN = 625*64 exactly, no clamp needed
    int nbase   = blockIdx.y * BN;
    int ml = lane & 15, q = lane >> 4;

    f32x4 acc[2][4];
#pragma unroll
    for (int i = 0; i < 2; i++)
#pragma unroll
        for (int j = 0; j < 4; j++) acc[i][j] = (f32x4){0,0,0,0};

    // staging assignment: thread -> (row, chunk)
    int srow = tid >> 2, sc = tid & 3;          // A: 64 rows x 4 chunks = 256
    const ushort_t* bp0 = Bt + (size_t)(nbase + srow) * KTOT + sc * 8;
    const ushort_t* bp1 = Bt + (size_t)(nbase + 64 + srow) * KTOT + sc * 8;

    uint4 pa[2], pb0[2], pb1[2];

    auto g_load = [&](int kb, int s) {
        const ushort_t* ap = (kb < NB * DD)
            ? vb + (size_t)(rowbase + srow) * (NB * DD) + kb + sc * 8
            : xb + (size_t)(rowbase + srow) * DD + (kb - NB * DD) + sc * 8;
        pa[s]  = *(const uint4*)ap;
        pb0[s] = *(const uint4*)(bp0 + kb);
        pb1[s] = *(const uint4*)(bp1 + kb);
    };

    int soff = srow * BK + ((sc ^ ((srow >> 2) & 3)) * 8);

    // fragment read offsets (swizzled)
    int aoff[2], boff[4];
#pragma unroll
    for (int i = 0; i < 2; i++) {
        int m = wr * 32 + i * 16 + ml;
        aoff[i] = m * BK + ((q ^ ((m >> 2) & 3)) * 8);
    }
#pragma unroll
    for (int j = 0; j < 4; j++) {
        int n = wc * 64 + j * 16 + ml;
        boff[j] = n * BK + ((q ^ ((n >> 2) & 3)) * 8);
    }

    g_load(0, 0);
    g_load(BK, 1);
#pragma unroll 2
    for (int it = 0; it < NITER; it++) {
        int s = it & 1;
        *(uint4*)&As[s][soff] = pa[s];               // waits vmcnt for 2-iter-old load
        *(uint4*)&Bs[s][soff] = pb0[s];
        *(uint4*)&Bs[s][64 * BK + soff] = pb1[s];
        if (it + 2 < NITER) g_load((it + 2) * BK, s);
        __syncthreads();                              // buf[s] visible; prior reads drained

        bf16x8 af[2], bf[4];
#pragma unroll
        for (int i = 0; i < 2; i++) af[i] = *(const bf16x8*)&As[s][aoff[i]];
#pragma unroll
        for (int j = 0; j < 4; j++) bf[j] = *(const bf16x8*)&Bs[s][boff[j]];
#pragma unroll
        for (int i = 0; i < 2; i++)
#pragma unroll
            for (int j = 0; j < 4; j++)
                acc[i][j] = __builtin_amdgcn_mfma_f32_16x16x32_bf16(af[i], bf[j], acc[i][j], 0, 0, 0);
    }

    // epilogue: C layout col=lane&15, row=(lane>>4)*4+reg
#pragma unroll
    for (int i = 0; i < 2; i++) {
#pragma unroll
        for (int r = 0; r < 4; r++) {
            int ng = rowbase + wr * 32 + i * 16 + q * 4 + r;
#pragma unroll
            for (int j = 0; j < 4; j++) {
                int o = nbase + wc * 64 + j * 16 + ml;
                float vv = acc[i][j][r] + bias[o];
                out[(size_t)ng * DD + o] = fmaxf(vv, 0.0f);
            }
        }
    }
}

extern "C" void kernel_launch(void* const* d_in, const int* in_sizes, int n_in,
                              void* d_out, int out_size, void* d_ws, size_t ws_size,
                              hipStream_t stream) {
    const float* x     = (const float*)d_in[0];
    const float* bases = (const float*)d_in[1];
    const float* coeff = (const float*)d_in[2];
    const float* lw    = (const float*)d_in[3];
    const float* bias  = (const float*)d_in[4];
    const int*   esrc  = (const int*)d_in[5];
    const int*   edst  = (const int*)d_in[6];
    float* out = (float*)d_out;

    char* ws = (char*)d_ws;
    ushort_t*     vb      = (ushort_t*)(ws);
    ushort_t*     xb      = (ushort_t*)(ws + 81920000);
    ushort_t*     Bt      = (ushort_t*)(ws + 102400000);
    int*          deg     = (int*)(ws + 103055360);
    int*          offsets = (int*)(ws + 105775360);
    int*          cursor  = (int*)(ws + 105935376);
    unsigned int* recs    = (unsigned int*)(ws + 106095376);
    int*          bsum    = (int*)(ws + 109295376);

    hipMemsetAsync(deg, 0, (size_t)RR * NN * sizeof(int), stream);

    int ne = RR * EE;
    k_prep<<<CAST_BLKS + DEG_BLKS, 256, 0, stream>>>(x, bases, lw, edst, xb, Bt, deg);
    k_scanA<<<SCAN_BLK, 256, 0, stream>>>(deg, offsets, bsum);
    k_scanB<<<SCAN_BLK, 256, 0, stream>>>(bsum, offsets, cursor);
    k_escatter<<<(ne + 255) / 256, 256, 0, stream>>>(esrc, edst, cursor, recs);
    k_gather<<<NN / 4, 256, 0, stream>>>(xb, coeff, deg, offsets, recs, vb);
    dim3 ggrid(NN / BM, DD / BN);
    k_gemm<<<ggrid, 256, 0, stream>>>(vb, xb, Bt, bias, out);
}

// Round 10
// 304.474 us; speedup vs baseline: 1.4434x; 1.4434x over previous
//
#include <hip/hip_runtime.h>

#define NN   40000
#define RR   16
#define EE   50000
#define DD   256
#define NB   4
#define KTOT (NB*DD + DD)   // 1280
#define BM   64
#define BN   128
#define BK   32
#define NITER (KTOT/BK)     // 40

#define SCAN_BLK  40
#define SCAN_ELEM 1024      // elements per scan block (40*1024 >= NN)

typedef __bf16 bf16x8 __attribute__((ext_vector_type(8)));
typedef float  f32x4  __attribute__((ext_vector_type(4)));
typedef float  f32x2  __attribute__((ext_vector_type(2)));
typedef unsigned short ushort_t;

__device__ inline unsigned short f2bf(float f) {
    unsigned int b = __builtin_bit_cast(unsigned int, f);
    b += 0x7FFFu + ((b >> 16) & 1u);      // round-to-nearest-even
    return (unsigned short)(b >> 16);
}

// ws layout (bytes), all 16B-aligned:
//   vb      @ 0            NN*1024 bf16 =  81,920,000
//   xb      @ 81,920,000   NN*256  bf16 =  20,480,000
//   Bt      @ 102,400,000  256*1280 bf16 =    655,360
//   deg     @ 103,055,360  RR*NN int    =   2,560,000
//   offsets @ 105,775,360  (NN+1) int
//   cursor  @ 105,935,376  NN int
//   recs    @ 106,095,376  RR*EE u32    =   3,200,000
//   bsum    @ 109,295,376  SCAN_BLK int

#define CAST_BLKS ((NN * DD / 4 + DD * KTOT + 255) / 256)   // 11280
#define DEG_BLKS  ((RR * EE + 255) / 256)                   // 3125

// fused: xb cast + Bt build + per-relation degree histogram
__global__ __launch_bounds__(256) void k_prep(const float* __restrict__ x,
                                              const float* __restrict__ bases,
                                              const float* __restrict__ lw,
                                              const int* __restrict__ edst,
                                              ushort_t* __restrict__ xb,
                                              ushort_t* __restrict__ Bt,
                                              int* __restrict__ deg) {
    int b = blockIdx.x;
    if (b < CAST_BLKS) {
        int t = b * 256 + threadIdx.x;
        const int NX = NN * DD / 4;
        if (t < NX) {
            float4 f = *(const float4*)(x + (size_t)t * 4);
            ushort4 o;
            o.x = f2bf(f.x); o.y = f2bf(f.y); o.z = f2bf(f.z); o.w = f2bf(f.w);
            *(ushort4*)(xb + (size_t)t * 4) = o;
        } else {
            int u = t - NX;                // u = o*1280 + k
            if (u < DD * KTOT) {
                int o = u / KTOT, k = u - o * KTOT;
                float f = (k < NB * DD) ? bases[(size_t)k * DD + o]
                                        : lw[(size_t)(k - NB * DD) * DD + o];
                Bt[u] = f2bf(f);
            }
        }
    } else {
        int e = (b - CAST_BLKS) * 256 + threadIdx.x;
        if (e < RR * EE) {
            int r = e / EE;
            atomicAdd(&deg[r * NN + edst[e]], 1);
        }
    }
}

// phase A: per-node degree sum (from deg directly) + block-local exclusive scan
__global__ __launch_bounds__(256) void k_scanA(const int* __restrict__ deg,
                                               int* __restrict__ offsets,
                                               int* __restrict__ bsum) {
    __shared__ int part[256];
    int t = threadIdx.x, b = blockIdx.x;
    int g = b * SCAN_ELEM + t * 4;
    int4 h = {0, 0, 0, 0};
    if (g < NN) {                          // NN%4==0 so g<NN implies g+3<NN
#pragma unroll
        for (int r = 0; r < RR; r++) {
            int4 d = *(const int4*)(deg + (size_t)r * NN + g);
            h.x += d.x; h.y += d.y; h.z += d.z; h.w += d.w;
        }
    }
    int s = h.x + h.y + h.z + h.w;
    part[t] = s;
    __syncthreads();
    for (int off = 1; off < 256; off <<= 1) {
        int v = (t >= off) ? part[t - off] : 0;
        __syncthreads();
        part[t] += v;
        __syncthreads();
    }
    int ex = part[t] - s;
    if (g < NN) {
        int4 o;
        o.x = ex;
        o.y = ex + h.x;
        o.z = ex + h.x + h.y;
        o.w = ex + h.x + h.y + h.z;
        *(int4*)(offsets + g) = o;
    }
    if (t == 255) bsum[b] = part[255];
}

// phase B: add block-prefix base, mirror into cursor, write offsets[NN]
__global__ __launch_bounds__(256) void k_scanB(const int* __restrict__ bsum,
                                               int* __restrict__ offsets,
                                               int* __restrict__ cursor) {
    __shared__ int sbase, stot;
    int t = threadIdx.x, b = blockIdx.x;
    if (t == 0) {
        int acc = 0, base = 0;
        for (int i = 0; i < SCAN_BLK; i++) {
            if (i == b) base = acc;
            acc += bsum[i];
        }
        sbase = base;
        stot = acc;
    }
    __syncthreads();
    int base = sbase;
    int g = b * SCAN_ELEM + t * 4;
    if (g < NN) {
        int4 o = *(const int4*)(offsets + g);
        o.x += base; o.y += base; o.z += base; o.w += base;
        *(int4*)(offsets + g) = o;
        *(int4*)(cursor + g) = o;
    }
    if (b == SCAN_BLK - 1 && t == 0) offsets[NN] = stot;
}

__global__ __launch_bounds__(256) void k_escatter(const int* __restrict__ esrc,
                                                  const int* __restrict__ edst,
                                                  int* __restrict__ cursor,
                                                  unsigned int* __restrict__ recs) {
    int e = blockIdx.x * blockDim.x + threadIdx.x;
    if (e >= RR * EE) return;
    int r = e / EE;
    int d = edst[e];
    int pos = atomicAdd(&cursor[d], 1);
    recs[pos] = (unsigned int)esrc[e] | ((unsigned int)r << 16);
}

// one wave per dst node; per-wave weight table in LDS; 4-edge unrolled
__global__ __launch_bounds__(256) void k_gather(const ushort_t* __restrict__ xb,
                                                const float* __restrict__ coeff,
                                                const int* __restrict__ deg,
                                                const int* __restrict__ offsets,
                                                const unsigned int* __restrict__ recs,
                                                ushort_t* __restrict__ vb) {
    __shared__ float wtab[4][64];
    int lane = threadIdx.x & 63;
    int wv   = threadIdx.x >> 6;
    int n    = __builtin_amdgcn_readfirstlane(blockIdx.x * 4 + wv);

    {   // wtab[wv][r*4+b] = coeff[r*4+b] / max(deg[r][n],1)
        int r  = lane >> 2;
        int dg = deg[r * NN + n];
        float inv = 1.0f / (float)(dg > 0 ? dg : 1);
        wtab[wv][lane] = coeff[lane] * inv;
    }

    int beg = offsets[n], end = offsets[n + 1];
    f32x2 a[4][2];
#pragma unroll
    for (int b = 0; b < 4; b++) { a[b][0] = (f32x2){0,0}; a[b][1] = (f32x2){0,0}; }

    const float* wrow = &wtab[wv][0];
    const ushort_t* xl = xb + lane * 4;

    auto acc_edge = [&](uint2 u, float4 w) {
        f32x2 lo, hi;
        lo.x = __builtin_bit_cast(float, u.x << 16);
        lo.y = __builtin_bit_cast(float, u.x & 0xFFFF0000u);
        hi.x = __builtin_bit_cast(float, u.y << 16);
        hi.y = __builtin_bit_cast(float, u.y & 0xFFFF0000u);
        a[0][0] = lo * (f32x2){w.x, w.x} + a[0][0];
        a[0][1] = hi * (f32x2){w.x, w.x} + a[0][1];
        a[1][0] = lo * (f32x2){w.y, w.y} + a[1][0];
        a[1][1] = hi * (f32x2){w.y, w.y} + a[1][1];
        a[2][0] = lo * (f32x2){w.z, w.z} + a[2][0];
        a[2][1] = hi * (f32x2){w.z, w.z} + a[2][1];
        a[3][0] = lo * (f32x2){w.w, w.w} + a[3][0];
        a[3][1] = hi * (f32x2){w.w, w.w} + a[3][1];
    };

    int ei = beg;
    for (; ei + 4 <= end; ei += 4) {
        unsigned int r0 = recs[ei + 0];
        unsigned int r1 = recs[ei + 1];
        unsigned int r2 = recs[ei + 2];
        unsigned int r3 = recs[ei + 3];
        uint2 u0 = *(const uint2*)(xl + (size_t)(r0 & 0xFFFFu) * DD);
        uint2 u1 = *(const uint2*)(xl + (size_t)(r1 & 0xFFFFu) * DD);
        uint2 u2 = *(const uint2*)(xl + (size_t)(r2 & 0xFFFFu) * DD);
        uint2 u3 = *(const uint2*)(xl + (size_t)(r3 & 0xFFFFu) * DD);
        float4 w0 = *(const float4*)&wrow[(r0 >> 16) * 4];
        float4 w1 = *(const float4*)&wrow[(r1 >> 16) * 4];
        float4 w2 = *(const float4*)&wrow[(r2 >> 16) * 4];
        float4 w3 = *(const float4*)&wrow[(r3 >> 16) * 4];
        acc_edge(u0, w0);
        acc_edge(u1, w1);
        acc_edge(u2, w2);
        acc_edge(u3, w3);
    }
    for (; ei < end; ei++) {
        unsigned int r0 = recs[ei];
        uint2 u0 = *(const uint2*)(xl + (size_t)(r0 & 0xFFFFu) * DD);
        float4 w0 = *(const float4*)&wrow[(r0 >> 16) * 4];
        acc_edge(u0, w0);
    }

    ushort_t* vr = vb + (size_t)n * (NB * DD) + lane * 4;
#pragma unroll
    for (int b = 0; b < 4; b++) {
        ushort4 o;
        o.x = f2bf(a[b][0].x); o.y = f2bf(a[b][0].y);
        o.z = f2bf(a[b][1].x); o.w = f2bf(a[b][1].y);
        *(ushort4*)(vr + b * DD) = o;
    }
}

// MFMA GEMM: out[40000][256] = relu([vb | xb] @ Bt^T + bias)
// block tile 64x128 (grid 625x2), 4 waves 2x2, wave tile 32x64; BK=32.
// Manually peeled even/odd LDS double-buffer with NAMED scalar prefetch regs
// (arrays + dynamic index caused scratch spill in R7/R9). Pipeline:
//   write buf[s] (waits vmcnt of load issued 2 iters ago ~2 compute phases)
//   -> reload stage s for it+2 -> barrier -> mfma from buf[s].
__global__ __launch_bounds__(256) void k_gemm(const ushort_t* __restrict__ vb,
                                              const ushort_t* __restrict__ xb,
                                              const ushort_t* __restrict__ Bt,
                                              const float* __restrict__ bias,
                                              float* __restrict__ out) {
    __shared__ ushort_t As[2][BM * BK];   // 2 x 4 KB
    __shared__ ushort_t Bs[2][BN * BK];   // 2 x 8 KB
    int tid  = threadIdx.x;
    int lane = tid & 63;
    int w    = tid >> 6;
    int wr   = w >> 1, wc = w & 1;     // wave tile: rows wr*32.., cols wc*64..
    int rowbase = blockIdx.x * BM;     // NN = 625*64 exactly, no clamp needed
    int nbase   = blockIdx.y * BN;
    int ml = lane & 15, q = lane >> 4;

    f32x4 acc[2][4];
#pragma unroll
    for (int i = 0; i < 2; i++)
#pragma unroll
        for (int j = 0; j < 4; j++) acc[i][j] = (f32x4){0,0,0,0};

    // staging assignment: thread -> (row, chunk); A: 64 rows x 4 chunks
    int srow = tid >> 2, sc = tid & 3;
    const ushort_t* bp0 = Bt + (size_t)(nbase + srow) * KTOT + sc * 8;
    const ushort_t* bp1 = Bt + (size_t)(nbase + 64 + srow) * KTOT + sc * 8;

    auto aptr = [&](int kb) {
        return (kb < NB * DD)
            ? vb + (size_t)(rowbase + srow) * (NB * DD) + kb + sc * 8
            : xb + (size_t)(rowbase + srow) * DD + (kb - NB * DD) + sc * 8;
    };

    int soff = srow * BK + ((sc ^ ((srow >> 2) & 3)) * 8);

    // fragment read offsets (swizzled)
    int aoff[2], boff[4];
#pragma unroll
    for (int i = 0; i < 2; i++) {
        int m = wr * 32 + i * 16 + ml;
        aoff[i] = m * BK + ((q ^ ((m >> 2) & 3)) * 8);
    }
#pragma unroll
    for (int j = 0; j < 4; j++) {
        int n = wc * 64 + j * 16 + ml;
        boff[j] = n * BK + ((q ^ ((n >> 2) & 3)) * 8);
    }

    // prologue: fill both stages (named scalars — no spillable arrays)
    uint4 a_e  = *(const uint4*)aptr(0);
    uint4 b0_e = *(const uint4*)(bp0);
    uint4 b1_e = *(const uint4*)(bp1);
    uint4 a_o  = *(const uint4*)aptr(BK);
    uint4 b0_o = *(const uint4*)(bp0 + BK);
    uint4 b1_o = *(const uint4*)(bp1 + BK);

    for (int it = 0; it < NITER; it += 2) {
        // ---------------- even stage: buffer 0 ----------------
        *(uint4*)&As[0][soff]           = a_e;
        *(uint4*)&Bs[0][soff]           = b0_e;
        *(uint4*)&Bs[0][64 * BK + soff] = b1_e;
        {
            int kb2 = (it + 2) * BK;
            if (kb2 < KTOT) {
                a_e  = *(const uint4*)aptr(kb2);
                b0_e = *(const uint4*)(bp0 + kb2);
                b1_e = *(const uint4*)(bp1 + kb2);
            }
        }
        __syncthreads();
        {
            bf16x8 af[2], bf[4];
#pragma unroll
            for (int i = 0; i < 2; i++) af[i] = *(const bf16x8*)&As[0][aoff[i]];
#pragma unroll
            for (int j = 0; j < 4; j++) bf[j] = *(const bf16x8*)&Bs[0][boff[j]];
#pragma unroll
            for (int i = 0; i < 2; i++)
#pragma unroll
                for (int j = 0; j < 4; j++)
                    acc[i][j] = __builtin_amdgcn_mfma_f32_16x16x32_bf16(af[i], bf[j], acc[i][j], 0, 0, 0);
        }
        // ---------------- odd stage: buffer 1 ----------------
        *(uint4*)&As[1][soff]           = a_o;
        *(uint4*)&Bs[1][soff]           = b0_o;
        *(uint4*)&Bs[1][64 * BK + soff] = b1_o;
        {
            int kb3 = (it + 3) * BK;
            if (kb3 < KTOT) {
                a_o  = *(const uint4*)aptr(kb3);
                b0_o = *(const uint4*)(bp0 + kb3);
                b1_o = *(const uint4*)(bp1 + kb3);
            }
        }
        __syncthreads();
        {
            bf16x8 af[2], bf[4];
#pragma unroll
            for (int i = 0; i < 2; i++) af[i] = *(const bf16x8*)&As[1][aoff[i]];
#pragma unroll
            for (int j = 0; j < 4; j++) bf[j] = *(const bf16x8*)&Bs[1][boff[j]];
#pragma unroll
            for (int i = 0; i < 2; i++)
#pragma unroll
                for (int j = 0; j < 4; j++)
                    acc[i][j] = __builtin_amdgcn_mfma_f32_16x16x32_bf16(af[i], bf[j], acc[i][j], 0, 0, 0);
        }
    }

    // epilogue: C layout col=lane&15, row=(lane>>4)*4+reg
#pragma unroll
    for (int i = 0; i < 2; i++) {
#pragma unroll
        for (int r = 0; r < 4; r++) {
            int ng = rowbase + wr * 32 + i * 16 + q * 4 + r;
#pragma unroll
            for (int j = 0; j < 4; j++) {
                int o = nbase + wc * 64 + j * 16 + ml;
                float vv = acc[i][j][r] + bias[o];
                out[(size_t)ng * DD + o] = fmaxf(vv, 0.0f);
            }
        }
    }
}

extern "C" void kernel_launch(void* const* d_in, const int* in_sizes, int n_in,
                              void* d_out, int out_size, void* d_ws, size_t ws_size,
                              hipStream_t stream) {
    const float* x     = (const float*)d_in[0];
    const float* bases = (const float*)d_in[1];
    const float* coeff = (const float*)d_in[2];
    const float* lw    = (const float*)d_in[3];
    const float* bias  = (const float*)d_in[4];
    const int*   esrc  = (const int*)d_in[5];
    const int*   edst  = (const int*)d_in[6];
    float* out = (float*)d_out;

    char* ws = (char*)d_ws;
    ushort_t*     vb      = (ushort_t*)(ws);
    ushort_t*     xb      = (ushort_t*)(ws + 81920000);
    ushort_t*     Bt      = (ushort_t*)(ws + 102400000);
    int*          deg     = (int*)(ws + 103055360);
    int*          offsets = (int*)(ws + 105775360);
    int*          cursor  = (int*)(ws + 105935376);
    unsigned int* recs    = (unsigned int*)(ws + 106095376);
    int*          bsum    = (int*)(ws + 109295376);

    hipMemsetAsync(deg, 0, (size_t)RR * NN * sizeof(int), stream);

    int ne = RR * EE;
    k_prep<<<CAST_BLKS + DEG_BLKS, 256, 0, stream>>>(x, bases, lw, edst, xb, Bt, deg);
    k_scanA<<<SCAN_BLK, 256, 0, stream>>>(deg, offsets, bsum);
    k_scanB<<<SCAN_BLK, 256, 0, stream>>>(bsum, offsets, cursor);
    k_escatter<<<(ne + 255) / 256, 256, 0, stream>>>(esrc, edst, cursor, recs);
    k_gather<<<NN / 4, 256, 0, stream>>>(xb, coeff, deg, offsets, recs, vb);
    dim3 ggrid(NN / BM, DD / BN);
    k_gemm<<<ggrid, 256, 0, stream>>>(vb, xb, Bt, bias, out);
}